// Round 8
// baseline (8672.279 us; speedup 1.0000x reference)
//
#include <hip/hip_runtime.h>
#include <stdint.h>

// SpikingNetwork B=128 T=128 I=1024 dims 2048/2048/1024, beta=0.9, thr=1.0.
// R12: R11 (6.31ms, 64m x 64n tiles, 4m x 4n/thr, L0 ksplit2 in-block, L1/L2
// ksplit4 = 2 in-block + cross-block pair, LDS merge + global partials) +
// latency hiding via register-prefetch staging: chunk ch+1's global loads are
// issued right after the pre-FMA barrier and fly under the 8192-cy FMA window;
// the WRITE->LDS phase at the top of the next chunk then finds them landed.
// This is R7's pipeline, which was correct but spilled at the 128-VGPR cap;
// current geometry caps at 256 VGPR (launch_bounds(512,2)) with 92 in use, so
// the +64 prefetch regs fit. FMA k4-loop unroll 4->8 for deeper ds_read ILP.
// DAG bit-identical: 512-k ascending fmac chains, ((P0+P1)+P2)+P3 __fadd_rn
// merges in order, LIF rounding verbatim. Spikes bitmasks + done-counters.

#define TT   128
#define NB   128
#define DD2  1024

// ws layout (u32 units)
#define SPK0_OFF 0u
#define SPK1_OFF (128u*128u*64u)                 // 1,048,576
#define PART_OFF (2u*128u*128u*64u)              // 2,097,152
#define NHELP    96u                             // 96 slots x 8192 floats (32KB)
#define FLG_OFF  (PART_OFF + NHELP*8192u)        // 2,883,584
#define NFLG     1536u                           // pflag512 oflag512 done0 2x128 done1 2x128
#define WS_NEED_BYTES ((size_t)(FLG_OFF + NFLG) * 4u)   // 11,540,480

__device__ __forceinline__ void wait_ge(uint32_t* p, uint32_t tgt){
  while (__hip_atomic_load(p, __ATOMIC_ACQUIRE, __HIP_MEMORY_SCOPE_AGENT) < tgt)
    __builtin_amdgcn_s_sleep(1);
}

// LDS column swizzle for lA: 4-float granules (b128-aligned); constant over a
// 4-aligned k-granule. Spreads staging stores and fma reads across banks.
__device__ __forceinline__ constexpr int fswz(int k){
  return (k & 16) | ((k ^ (k >> 3)) & 12);
}

__global__ void sentinel_kernel(float* o){ o[0] = 42.0f; }   // ws-too-small marker

__global__ __launch_bounds__(512, 2) void snn_kernel(
    const float* __restrict__ x,
    const float* __restrict__ W0, const float* __restrict__ b0,
    const float* __restrict__ W1, const float* __restrict__ b1,
    const float* __restrict__ W2, const float* __restrict__ b2,
    float* __restrict__ out, uint32_t* __restrict__ ws)
{
  __shared__ __align__(16) float lA[2][128][68];   // per-half [k][m^swz], 69,632 B
  __shared__ __align__(16) float lB[2][64][132];   // per-half [n][k],     67,584 B
  __shared__ uint32_t lBits[128];                  // 64 rows x 2 words

  const int tid  = threadIdx.x;
  const int h    = tid >> 8;       // half: 0/1 (k-part within block)
  const int t256 = tid & 255;
  const int tm   = t256 & 15;      // m-group: rows tm*4 .. +3
  const int tn   = t256 >> 4;      // n-group: cols tn*4 .. +3
  const int bid  = blockIdx.x;

  uint32_t* spikes0  = ws + SPK0_OFF;
  uint32_t* spikes1  = ws + SPK1_OFF;
  float*    partials = (float*)(ws + PART_OFF);   // [NHELP][8192]
  uint32_t* flg   = ws + FLG_OFF;
  uint32_t* pflag = flg;            // [512] helper(bid)->owner: partials for t ready
  uint32_t* oflag = flg + 512;      // [512] owner(bid)->helper: consumed through t
  uint32_t* done0 = flg + 1024;     // [2][128] per m-half, target 32
  uint32_t* done1 = flg + 1280;     // [2][128] per m-half, target 32

  int group, pairk, tl, m0, n0, K, hslot;
  const float *Wl, *bl;
  const uint32_t* spkIn; uint32_t* spkOut;
  uint32_t *dIn, *dOut;
  if (bid < 64) {           // L0: 64 tiles 64x64, K=1024, ksplit2 in-block
    group=0; pairk=0; tl=bid;
    m0=(tl>>5)*64; n0=(tl&31)*64; K=1024; Wl=W0; bl=b0;
    spkIn=nullptr; spkOut=spikes0; dIn=nullptr; dOut=done0+(m0>>6)*128; hslot=-1;
  } else if (bid < 192) {   // L1: 64 tiles 64x64, K=2048, ksplit4 (2 blocks/tile)
    group=1; int rel=bid-64; pairk=rel&1; tl=rel>>1;
    m0=(tl>>5)*64; n0=(tl&31)*64; K=2048; Wl=W1; bl=b1;
    spkIn=spikes0; spkOut=spikes1;
    dIn=done0+(m0>>6)*128; dOut=done1+(m0>>6)*128; hslot=tl;
  } else {                  // L2: 32 tiles 64x64, K=2048, ksplit4
    group=2; int rel=bid-192; pairk=rel&1; tl=rel>>1;
    m0=(tl>>4)*64; n0=(tl&15)*64; K=2048; Wl=W2; bl=b2;
    spkIn=spikes1; spkOut=nullptr;
    dIn=done1+(m0>>6)*128; dOut=nullptr; hslot=64+tl;
  }
  const bool helper = (pairk == 1);   // odd block of a pair: ships P2,P3
  const int  K0     = (pairk*2 + h)*512;

  float bias[4];
  #pragma unroll
  for (int c = 0; c < 4; ++c) bias[c] = bl[n0 + tn*4 + c];

  float vst[4][4];   // membrane potential (LIF by owner h=0 threads)
  #pragma unroll
  for (int r = 0; r < 4; ++r)
    #pragma unroll
    for (int c = 0; c < 4; ++c) vst[r][c] = 0.f;

  // staging decomposition: idx = t256 + it*256 -> kq = t256&31 (const),
  // row = (t256>>5) + it*8. Precompute bases.
  const int s_kq4 = (t256 & 31) * 4;     // float offset along 128-k chunk
  const int s_r0  = t256 >> 5;           // row base (0..7), +it*8

  // spike-expansion mapping (R11 verbatim): 4 rows x 8 k per thread
  const int e_mq   = t256 & 15;
  const int e_sub  = t256 >> 4;
  const int e_wsub = e_sub & 3;
  const int e_kq8  = e_sub >> 2;
  const int e_kloc = e_wsub*32 + e_kq8*8;

  float (*cA)[68]  = lA[h];
  float (*cB)[132] = lB[h];
  float* ex = &lA[1][0][0];   // in-block merge buffer (16KB of helper-half lA)

  float4   pb_[8];    // prefetched B chunk (32 VGPR)
  float4   pa_[8];    // prefetched A chunk, group 0 (32 VGPR)
  uint32_t pw_[4];    // prefetched spike words, groups 1/2

#define ISSUE(CH) do {                                                         \
    const int kb_ = K0 + (CH)*128;                                             \
    const float* gb_ = Wl + (size_t)(n0 + s_r0)*K + kb_ + s_kq4;               \
    _Pragma("unroll")                                                          \
    for (int it = 0; it < 8; ++it)                                             \
      pb_[it] = *(const float4*)(gb_ + (size_t)it*8*K);                        \
    if (group == 0) {                                                          \
      const float* ga_ = x + ((size_t)(m0 + s_r0)*TT + t)*1024 + kb_ + s_kq4;  \
      _Pragma("unroll")                                                        \
      for (int it = 0; it < 8; ++it)                                           \
        pa_[it] = *(const float4*)(ga_ + (size_t)it*8*TT*1024);                \
    } else {                                                                   \
      const size_t rb_ = ((size_t)t*NB + m0 + e_mq*4)*64 + (kb_>>5) + e_wsub;  \
      _Pragma("unroll")                                                        \
      for (int j = 0; j < 4; ++j)                                              \
        pw_[j] = __hip_atomic_load(&spkIn[rb_ + (size_t)j*64],                 \
                                   __ATOMIC_RELAXED, __HIP_MEMORY_SCOPE_AGENT);\
    }                                                                          \
  } while (0)

#define WRITE_LDS() do {                                                       \
    _Pragma("unroll")                                                          \
    for (int it = 0; it < 8; ++it)                                             \
      *(float4*)&cB[s_r0 + it*8][s_kq4] = pb_[it];                             \
    if (group == 0) {                                                          \
      const int k0_ = s_kq4, sw_ = fswz(k0_);                                  \
      _Pragma("unroll")                                                        \
      for (int it = 0; it < 8; ++it) {                                         \
        const int col = (s_r0 + it*8) ^ sw_;                                   \
        cA[k0_+0][col] = pa_[it].x; cA[k0_+1][col] = pa_[it].y;                \
        cA[k0_+2][col] = pa_[it].z; cA[k0_+3][col] = pa_[it].w;                \
      }                                                                        \
    } else {                                                                   \
      _Pragma("unroll")                                                        \
      for (int i = 0; i < 8; ++i) {                                            \
        const int k_ = e_kloc + i;                                             \
        const int sh_ = k_ & 31;                                               \
        float4 f_;                                                             \
        f_.x = ((pw_[0] >> sh_) & 1u) ? 1.0f : 0.0f;                           \
        f_.y = ((pw_[1] >> sh_) & 1u) ? 1.0f : 0.0f;                           \
        f_.z = ((pw_[2] >> sh_) & 1u) ? 1.0f : 0.0f;                           \
        f_.w = ((pw_[3] >> sh_) & 1u) ? 1.0f : 0.0f;                           \
        *(float4*)&cA[k_][(e_mq*4) ^ fswz(k_)] = f_;                           \
      }                                                                        \
    }                                                                          \
  } while (0)

  for (int t = 0; t < TT; ++t) {
    if (dIn) {  // previous layer's spikes for this m-half must be complete
      if (tid == 0) wait_ge(&dIn[t], 32u);
      __syncthreads();
    }

    float acc[4][4];   // ONE 512-k chain per half
    #pragma unroll
    for (int r = 0; r < 4; ++r)
      #pragma unroll
      for (int c = 0; c < 4; ++c) acc[r][c] = 0.f;

    ISSUE(0);   // cold prologue: chunk 0's latency exposed once per t

    #pragma unroll 1
    for (int ch = 0; ch < 4; ++ch) {            // 4 chunks of 128 k
      WRITE_LDS();          // regs landed (first chunk: waits; rest: hidden)
      __syncthreads();
      if (ch < 3) ISSUE(ch+1);   // loads fly under the FMA window below

      // ---- FMA micro-kernel: 128 k x (4m x 4n), sequential ascending k
      #pragma unroll 8
      for (int k4 = 0; k4 < 32; ++k4) {
        const int kbase = k4*4;
        const int sw = fswz(kbase);           // constant over the 4 sub-ks
        const float* pa = &cA[kbase][(tm*4) ^ sw];
        const float4 q0 = *(const float4*)&cB[tn*4+0][kbase];
        const float4 q1 = *(const float4*)&cB[tn*4+1][kbase];
        const float4 q2 = *(const float4*)&cB[tn*4+2][kbase];
        const float4 q3 = *(const float4*)&cB[tn*4+3][kbase];
        #pragma unroll
        for (int u = 0; u < 4; ++u) {
          const float4 a  = *(const float4*)(pa + u*68);
          const float b0v = (u==0) ? q0.x : (u==1) ? q0.y : (u==2) ? q0.z : q0.w;
          const float b1v = (u==0) ? q1.x : (u==1) ? q1.y : (u==2) ? q1.z : q1.w;
          const float b2v = (u==0) ? q2.x : (u==1) ? q2.y : (u==2) ? q2.z : q2.w;
          const float b3v = (u==0) ? q3.x : (u==1) ? q3.y : (u==2) ? q3.z : q3.w;
          acc[0][0] = __builtin_fmaf(a.x, b0v, acc[0][0]);
          acc[1][0] = __builtin_fmaf(a.y, b0v, acc[1][0]);
          acc[2][0] = __builtin_fmaf(a.z, b0v, acc[2][0]);
          acc[3][0] = __builtin_fmaf(a.w, b0v, acc[3][0]);
          acc[0][1] = __builtin_fmaf(a.x, b1v, acc[0][1]);
          acc[1][1] = __builtin_fmaf(a.y, b1v, acc[1][1]);
          acc[2][1] = __builtin_fmaf(a.z, b1v, acc[2][1]);
          acc[3][1] = __builtin_fmaf(a.w, b1v, acc[3][1]);
          acc[0][2] = __builtin_fmaf(a.x, b2v, acc[0][2]);
          acc[1][2] = __builtin_fmaf(a.y, b2v, acc[1][2]);
          acc[2][2] = __builtin_fmaf(a.z, b2v, acc[2][2]);
          acc[3][2] = __builtin_fmaf(a.w, b2v, acc[3][2]);
          acc[0][3] = __builtin_fmaf(a.x, b3v, acc[0][3]);
          acc[1][3] = __builtin_fmaf(a.y, b3v, acc[1][3]);
          acc[2][3] = __builtin_fmaf(a.z, b3v, acc[2][3]);
          acc[3][3] = __builtin_fmaf(a.w, b3v, acc[3][3]);
        }
      }
      __syncthreads();
    }

    if (helper) {
      // ship P2 (h=0) and P3 (h=1) raw; single-buffered vs owner's consumption
      if (t >= 1) { if (tid == 0) wait_ge(&oflag[bid-1], (uint32_t)t); __syncthreads(); }
      uint64_t* pb = (uint64_t*)(partials + (size_t)hslot*8192 + (size_t)h*4096) + t256*8;
      #pragma unroll
      for (int r = 0; r < 4; ++r)
        #pragma unroll
        for (int cq = 0; cq < 2; ++cq) {
          union { float f[2]; uint64_t u; } cv;
          cv.f[0] = acc[r][cq*2+0]; cv.f[1] = acc[r][cq*2+1];
          __hip_atomic_store(&pb[r*2+cq], cv.u, __ATOMIC_RELAXED, __HIP_MEMORY_SCOPE_AGENT);
        }
      __syncthreads();
      if (tid == 0) __hip_atomic_store(&pflag[bid], (uint32_t)(t+1), __ATOMIC_RELEASE, __HIP_MEMORY_SCOPE_AGENT);
      continue;
    }

    // ---- owner in-block merge: acc = P0 + P1 (ascending, __fadd_rn)
    if (h == 1) {
      #pragma unroll
      for (int r = 0; r < 4; ++r)
        *(float4*)&ex[t256*16 + r*4] = make_float4(acc[r][0], acc[r][1], acc[r][2], acc[r][3]);
    }
    __syncthreads();
    if (h == 0) {
      #pragma unroll
      for (int r = 0; r < 4; ++r)
        #pragma unroll
        for (int c = 0; c < 4; ++c)
          acc[r][c] = __fadd_rn(acc[r][c], ex[t256*16 + r*4 + c]);
    }

    // ---- L1/L2: fold helper's P2 entirely, then P3 (same order as R5)
    if (group != 0) {
      if (tid == 0) wait_ge(&pflag[bid+1], (uint32_t)(t+1));
      __syncthreads();
      if (h == 0) {
        uint64_t* p2 = (uint64_t*)(partials + (size_t)hslot*8192) + t256*8;
        uint64_t* p3 = (uint64_t*)(partials + (size_t)hslot*8192 + 4096) + t256*8;
        #pragma unroll
        for (int r = 0; r < 4; ++r)
          #pragma unroll
          for (int cq = 0; cq < 2; ++cq) {
            union { uint64_t u; float f[2]; } cv;
            cv.u = __hip_atomic_load(&p2[r*2+cq], __ATOMIC_RELAXED, __HIP_MEMORY_SCOPE_AGENT);
            acc[r][cq*2+0] = __fadd_rn(acc[r][cq*2+0], cv.f[0]);
            acc[r][cq*2+1] = __fadd_rn(acc[r][cq*2+1], cv.f[1]);
          }
        #pragma unroll
        for (int r = 0; r < 4; ++r)
          #pragma unroll
          for (int cq = 0; cq < 2; ++cq) {
            union { uint64_t u; float f[2]; } cv;
            cv.u = __hip_atomic_load(&p3[r*2+cq], __ATOMIC_RELAXED, __HIP_MEMORY_SCOPE_AGENT);
            acc[r][cq*2+0] = __fadd_rn(acc[r][cq*2+0], cv.f[0]);
            acc[r][cq*2+1] = __fadd_rn(acc[r][cq*2+1], cv.f[1]);
          }
      }
      __syncthreads();
      if (tid == 0) __hip_atomic_store(&oflag[bid], (uint32_t)(t+1), __ATOMIC_RELEASE, __HIP_MEMORY_SCOPE_AGENT);
    }

    if (group < 2) { if (tid < 128) lBits[tid] = 0; __syncthreads(); }

    // LIF: cur = acc + b (rn); v = 0.9*v + cur (mul+add rn, NO fma contraction);
    // spk = v > 1.0 strictly; v -= spk.  (owner h=0 threads hold the full tile)
    if (h == 0) {
      float sv[4][4], vv8[4][4];
      #pragma unroll
      for (int r = 0; r < 4; ++r) {
        uint32_t msk = 0;
        #pragma unroll
        for (int c = 0; c < 4; ++c) {
          float cur = __fadd_rn(acc[r][c], bias[c]);
          float vv  = __fadd_rn(__fmul_rn(0.9f, vst[r][c]), cur);
          float s   = (vv > 1.0f) ? 1.0f : 0.0f;
          vv = __fsub_rn(vv, s);
          vst[r][c] = vv;
          sv[r][c] = s; vv8[r][c] = vv;
          msk |= (s != 0.f) ? (1u << c) : 0u;
        }
        if (group < 2 && msk)
          atomicOr(&lBits[(tm*4 + r)*2 + (tn>>3)], msk << ((tn&7)*4));
      }
      if (group == 2) {
        #pragma unroll
        for (int r = 0; r < 4; ++r) {
          size_t o  = ((size_t)(m0 + tm*4 + r)*TT + t)*DD2 + n0 + tn*4;
          *(float4*)(out + o)  = make_float4(sv[r][0], sv[r][1], sv[r][2], sv[r][3]);
          size_t ov = (size_t)NB*TT*DD2 + o;
          *(float4*)(out + ov) = make_float4(vv8[r][0], vv8[r][1], vv8[r][2], vv8[r][3]);
        }
      }
    }

    if (group < 2) {
      __syncthreads();
      if (tid < 128)
        __hip_atomic_store(&spkOut[((size_t)t*NB + m0 + (tid>>1))*64 + (n0>>5) + (tid&1)],
                           lBits[tid], __ATOMIC_RELAXED, __HIP_MEMORY_SCOPE_AGENT);
      __syncthreads();
      if (tid == 0) __hip_atomic_fetch_add(&dOut[t], 1u, __ATOMIC_RELEASE, __HIP_MEMORY_SCOPE_AGENT);
    }
  }
#undef ISSUE
#undef WRITE_LDS
}

extern "C" void kernel_launch(void* const* d_in, const int* in_sizes, int n_in,
                              void* d_out, int out_size, void* d_ws, size_t ws_size,
                              hipStream_t stream) {
  (void)in_sizes; (void)n_in; (void)out_size;
  float* outf = (float*)d_out;
  if (ws_size < WS_NEED_BYTES) {            // diagnostic: absmax ~41 => ws too small
    sentinel_kernel<<<1, 1, 0, stream>>>(outf);
    return;
  }
  const float* x  = (const float*)d_in[0];
  const float* W0 = (const float*)d_in[1];
  const float* b0 = (const float*)d_in[2];
  const float* W1 = (const float*)d_in[3];
  const float* b1 = (const float*)d_in[4];
  const float* W2 = (const float*)d_in[5];
  const float* b2 = (const float*)d_in[6];
  uint32_t* ws = (uint32_t*)d_ws;

  // zero flags (spikes/partials are write-before-read; flags gate everything)
  hipMemsetAsync(ws + FLG_OFF, 0, NFLG * sizeof(uint32_t), stream);

  snn_kernel<<<256, 512, 0, stream>>>(x, W0, b0, W1, b1, W2, b2, outf, ws);
}